// Round 1
// baseline (103.035 us; speedup 1.0000x reference)
//
#include <hip/hip_runtime.h>

#define B_   16
#define NK_  256
#define NQ_  256
#define DK_  256
#define H_   128
#define DV_  256

// 2*log2(e): features prescaled so exp2(C2X*x) = e^{2x}
#define C2X 2.8853900817779268f
// log2(e) for softmax exp
#define L2E 1.4426950408889634f
#define MASKV -1.0e5f

typedef float f4 __attribute__((ext_vector_type(4)));

__device__ __forceinline__ float exp2_fast(float x) { return __builtin_amdgcn_exp2f(x); }
__device__ __forceinline__ float rcp_fast(float x)  { return __builtin_amdgcn_rcpf(x); }

// ---------------------------------------------------------------------------
// Kernel A: projections -> EXponentiated features.
// R8: W staging double-buffered (kc step 32, W_s[2]) with register prefetch:
// global loads for chunk c+1 are issued BEFORE the 32-k compute of chunk c,
// ds_write lands after -> VMEM latency hidden, 1 barrier/chunk (T14 pattern).
//   blocks 0..255   : kfE[b][k][h]      = exp2(C2X * (key  @ Wk))
//   blocks 256..511 : qE4[b][h/4][q][4] = exp2(C2X * (query @ Wq))
// ---------------------------------------------------------------------------
__global__ __launch_bounds__(256) void proj_kernel(
    const float* __restrict__ key, const float* __restrict__ query,
    const float* __restrict__ Wk,  const float* __restrict__ Wq,
    float* __restrict__ kfE, float* __restrict__ qE4)
{
    __shared__ alignas(16) float A_s[16 * 256];      // 16 KB
    __shared__ alignas(16) float W_s[2][32 * 128];   // 2 x 16 KB

    const int blk = blockIdx.x;
    const int tid = threadIdx.x;
    const bool isQ = blk >= 256;
    const int rb = (blk & 255) * 16;                 // flat row base (b*256 + row)

    const float* __restrict__ A = isQ ? query : key;
    const float* __restrict__ W = isQ ? Wq : Wk;

    // stage 16 x 256 input rows (coalesced float4, 4 per thread)
    {
        const f4* src = (const f4*)(A + (size_t)rb * DK_);
        f4* dst = (f4*)A_s;
#pragma unroll
        for (int j = 0; j < 4; ++j) dst[tid + 256 * j] = src[tid + 256 * j];
    }
    // preload W chunk 0 (32 k-rows x 128) into registers: 4 f4 per thread
    f4 wr0, wr1, wr2, wr3;
    {
        const f4* ws = (const f4*)W;
        wr0 = ws[tid]; wr1 = ws[tid + 256]; wr2 = ws[tid + 512]; wr3 = ws[tid + 768];
    }

    const int rg2 = (tid >> 5) << 1;                 // row base: 2 rows
    const int c4  = (tid & 31) << 2;                 // col base: 4 cols

    f4 acc0 = {0.f, 0.f, 0.f, 0.f}, acc1 = acc0;

    for (int c = 0; c < 8; ++c) {                    // 8 chunks of 32 k
        {   // commit prefetched chunk to LDS
            f4* wd = (f4*)&W_s[c & 1][0];
            wd[tid] = wr0; wd[tid + 256] = wr1; wd[tid + 512] = wr2; wd[tid + 768] = wr3;
        }
        __syncthreads();                             // W_s[c&1] visible; prev reads of this buf done at barrier c-1
        if (c < 7) {                                 // issue next chunk loads: hidden under compute below
            const f4* ws = (const f4*)(W + (size_t)(c + 1) * 32 * H_);
            wr0 = ws[tid]; wr1 = ws[tid + 256]; wr2 = ws[tid + 512]; wr3 = ws[tid + 768];
        }
        const float* Wb = &W_s[c & 1][0];
        const float* Ab = A_s + (c << 5);
#pragma unroll
        for (int k = 0; k < 32; k += 4) {
            f4 w0 = *(const f4*)(Wb + (k + 0) * H_ + c4);
            f4 w1 = *(const f4*)(Wb + (k + 1) * H_ + c4);
            f4 w2 = *(const f4*)(Wb + (k + 2) * H_ + c4);
            f4 w3 = *(const f4*)(Wb + (k + 3) * H_ + c4);
            f4 a0 = *(const f4*)(Ab + (rg2 + 0) * 256 + k);
            f4 a1 = *(const f4*)(Ab + (rg2 + 1) * 256 + k);
            acc0 += a0[0] * w0; acc1 += a1[0] * w0;
            acc0 += a0[1] * w1; acc1 += a1[1] * w1;
            acc0 += a0[2] * w2; acc1 += a1[2] * w2;
            acc0 += a0[3] * w3; acc1 += a1[3] * w3;
        }
    }

    f4 e0, e1;
#pragma unroll
    for (int cc = 0; cc < 4; ++cc) {
        e0[cc] = exp2_fast(C2X * acc0[cc]);
        e1[cc] = exp2_fast(C2X * acc1[cc]);
    }

    if (!isQ) {
        float* dst = kfE + (size_t)(rb + rg2) * H_ + c4;
        *(f4*)(dst)      = e0;
        *(f4*)(dst + H_) = e1;
    } else {
        const int b  = rb >> 8;
        const int q0 = (rb & 255) + rg2;
        f4* dst = (f4*)qE4 + ((size_t)(b * 32 + (c4 >> 2))) * NQ_ + q0;
        dst[0] = e0;                                  // query q0   : 4 h-values
        dst[1] = e1;                                  // query q0+1
    }
}

// ---------------------------------------------------------------------------
// Kernel B: fused scores + masked softmax + PV.
// R8: 8 k-rows/block, 512 blocks x 512 threads (8 waves, still 16 waves/CU,
// all 512 blocks co-resident at 2 blocks/CU, 40 KB LDS).
//   Phase 1: wave = (chunk c = wu>>1, row-half rh = wu&1): each eq f4 load
//            feeds 4 k-rows (16 rcp/load) -> eq L2 traffic 268->82 MB.
//   Phase 2: wave wu -> k-row wu softmax (8 rows).
//   Phase 3: 8 q-streams (wave = stream), value read ONCE per 8-row block
//            (268->67 MB); two-step LDS reduce in 32 KB region aliased
//            over the phase-1 score buffer.
// b/g mapping keeps the 2 co-resident blocks of a CU on different batches.
// ---------------------------------------------------------------------------
__global__ __launch_bounds__(512, 4) void attn_kernel(
    const float* __restrict__ kfE, const float* __restrict__ qE4,
    const float* __restrict__ value, const int* __restrict__ vlens,
    const float* __restrict__ wv, float* __restrict__ out)
{
    __shared__ alignas(16) float at_s[256 * 8];      // attn transposed [q][k]  8 KB
    __shared__ alignas(16) float scratch[8192];      // sc_s[8][260] (ph1-2) / red[4][8][256] (ph3)  32 KB

    const int x    = blockIdx.x;                     // 512 blocks
    const int g    = x >> 4;                         // k-octet 0..31
    const int b    = ((x & 15) + ((x >> 8) << 3)) & 15;  // x and x+256 -> different b
    const int k0   = g << 3;                         // 8 k-rows
    const int tid  = threadIdx.x;
    const int lane = tid & 63;
    const int wu   = __builtin_amdgcn_readfirstlane(tid >> 6);  // 0..7
    const int valid  = vlens[b];
    const int nchunk = (valid + 63) >> 6;            // 1..4

    // sum(wv): uniform addresses -> scalar loads
    float sumwv;
    {
        f4 sw = {0.f, 0.f, 0.f, 0.f};
#pragma unroll
        for (int i = 0; i < 32; ++i) sw += ((const f4*)wv)[i];
        sumwv = (sw[0] + sw[1]) + (sw[2] + sw[3]);
    }

    float* sc_s = scratch;                           // [8][260]

    // ---- Phase 1: wave (c, rh) -> 4 k-rows of one 64-q chunk.
    {
        const int c  = wu >> 1;                      // chunk: distinct SIMDs for small nchunk
        const int rh = wu & 1;                       // row half: rows rh*4 .. rh*4+3
        if (c < nchunk) {
            const float* ekb = kfE + ((size_t)(b * NK_ + k0 + rh * 4)) * H_;   // uniform -> s_load
            const f4*    eqp = (const f4*)qE4 + ((size_t)b << 13) + (c << 6) + lane;
            const f4*    wvf = (const f4*)wv;

            float acc[4][2];
#pragma unroll
            for (int r = 0; r < 4; ++r) { acc[r][0] = 0.f; acc[r][1] = 0.f; }

#pragma unroll 4
            for (int h4 = 0; h4 < 32; ++h4) {
                const f4 e  = eqp[h4 << 8];          // 1 vector load feeds 4 rows
                const f4 w4 = wvf[h4];               // s_load
#pragma unroll
                for (int r = 0; r < 4; ++r) {
                    const f4 ek = *(const f4*)(ekb + r * H_ + (h4 << 2));  // s_load
                    acc[r][0] = fmaf(w4[0], rcp_fast(fmaf(ek[0], e[0], 1.f)), acc[r][0]);
                    acc[r][1] = fmaf(w4[1], rcp_fast(fmaf(ek[1], e[1], 1.f)), acc[r][1]);
                    acc[r][0] = fmaf(w4[2], rcp_fast(fmaf(ek[2], e[2], 1.f)), acc[r][0]);
                    acc[r][1] = fmaf(w4[3], rcp_fast(fmaf(ek[3], e[3], 1.f)), acc[r][1]);
                }
            }
            const int q = (c << 6) + lane;
#pragma unroll
            for (int r = 0; r < 4; ++r)
                sc_s[(rh * 4 + r) * 260 + q] = sumwv - 2.f * (acc[r][0] + acc[r][1]);
        }
    }
    __syncthreads();

    // ---- Phase 2: in-wave masked softmax, wave wu -> k-row wu.
    {
        const float* row = sc_s + wu * 260;
        float s[4];
        float m = MASKV;
#pragma unroll
        for (int j = 0; j < 4; ++j) {
            const int q = (j << 6) + lane;
            s[j] = (q < valid) ? row[q] : MASKV;     // unwritten chunks never selected
            m = fmaxf(m, s[j]);
        }
#pragma unroll
        for (int off = 32; off >= 1; off >>= 1)
            m = fmaxf(m, __shfl_xor(m, off, 64));
        float ssum = 0.f;
#pragma unroll
        for (int j = 0; j < 4; ++j) {
            s[j] = exp2_fast(L2E * (s[j] - m));      // masked -> 0
            ssum += s[j];
        }
#pragma unroll
        for (int off = 32; off >= 1; off >>= 1)
            ssum += __shfl_xor(ssum, off, 64);
        const float inv = rcp_fast(ssum);
#pragma unroll
        for (int j = 0; j < 4; ++j)
            at_s[(((j << 6) + lane) << 3) + wu] = s[j] * inv;
    }
    __syncthreads();

    // ---- Phase 3: out[b][k0+k][d] = sum_q attn[q][k] * value[b][q][d]
    // 8 q-streams (wave = stream), each value f4 read exactly once per block.
    float* red = scratch;                            // [4][8][256], aliases dead sc_s
    {
        const int d4 = lane << 2;
        const float* vb = value + (size_t)b * (NQ_ * DV_) + d4;
        f4 o[8];
#pragma unroll
        for (int k = 0; k < 8; ++k) o[k] = (f4){0.f, 0.f, 0.f, 0.f};
#pragma unroll 4
        for (int q = wu; q < valid; q += 8) {
            const f4 v   = *(const f4*)(vb + (size_t)q * DV_);
            const f4 alo = *(const f4*)(at_s + (q << 3));      // uniform b128 broadcast
            const f4 ahi = *(const f4*)(at_s + (q << 3) + 4);
            o[0] += alo[0] * v; o[1] += alo[1] * v;
            o[2] += alo[2] * v; o[3] += alo[3] * v;
            o[4] += ahi[0] * v; o[5] += ahi[1] * v;
            o[6] += ahi[2] * v; o[7] += ahi[3] * v;
        }
        if (wu < 4) {                                // streams 0-3 write partials
            float* rp = red + (wu << 11) + d4;
#pragma unroll
            for (int k = 0; k < 8; ++k) *(f4*)(rp + (k << 8)) = o[k];
        }
    }
    __syncthreads();
    {
        const int d4 = lane << 2;
        if (wu >= 4) {                               // streams 4-7 accumulate in
            // o[] survives in registers across the barrier
            float* rp = red + ((wu - 4) << 11) + d4;
            // recompute nothing: o lives in this scope via the block above?  (kept live below)
        }
    }
    // NOTE: o[] must stay live for wu>=4 accumulation -> do it in one scope:
    // (the accumulate is folded here to keep register lifetime explicit)
    {
        const int d4 = lane << 2;
        // redo of accumulate for wu>=4 happens in the same registers: see below
    }
    __syncthreads();
    {
        // final cross-stream reduce + store: wave wu -> k-row wu
        const int d4 = lane << 2;
        const float* rp = red + (wu << 8) + d4;
        f4 oo = *(const f4*)(rp)        + *(const f4*)(rp + 2048)
              + *(const f4*)(rp + 4096) + *(const f4*)(rp + 6144);
        *(f4*)(out + ((size_t)(b * NK_ + k0 + wu)) * DV_ + d4) = oo;
    }
}

// The phase-3 structure above was split awkwardly; provide the real kernel:
// (attn_kernel2 is the actual one launched — single clean scope for o[].)
__global__ __launch_bounds__(512, 4) void attn_kernel2(
    const float* __restrict__ kfE, const float* __restrict__ qE4,
    const float* __restrict__ value, const int* __restrict__ vlens,
    const float* __restrict__ wv, float* __restrict__ out)
{
    __shared__ alignas(16) float at_s[256 * 8];
    __shared__ alignas(16) float scratch[8192];

    const int x    = blockIdx.x;
    const int g    = x >> 4;
    const int b    = ((x & 15) + ((x >> 8) << 3)) & 15;
    const int k0   = g << 3;
    const int tid  = threadIdx.x;
    const int lane = tid & 63;
    const int wu   = __builtin_amdgcn_readfirstlane(tid >> 6);
    const int valid  = vlens[b];
    const int nchunk = (valid + 63) >> 6;

    float sumwv;
    {
        f4 sw = {0.f, 0.f, 0.f, 0.f};
#pragma unroll
        for (int i = 0; i < 32; ++i) sw += ((const f4*)wv)[i];
        sumwv = (sw[0] + sw[1]) + (sw[2] + sw[3]);
    }

    float* sc_s = scratch;

    // Phase 1
    {
        const int c  = wu >> 1;
        const int rh = wu & 1;
        if (c < nchunk) {
            const float* ekb = kfE + ((size_t)(b * NK_ + k0 + rh * 4)) * H_;
            const f4*    eqp = (const f4*)qE4 + ((size_t)b << 13) + (c << 6) + lane;
            const f4*    wvf = (const f4*)wv;
            float acc[4][2];
#pragma unroll
            for (int r = 0; r < 4; ++r) { acc[r][0] = 0.f; acc[r][1] = 0.f; }
#pragma unroll 4
            for (int h4 = 0; h4 < 32; ++h4) {
                const f4 e  = eqp[h4 << 8];
                const f4 w4 = wvf[h4];
#pragma unroll
                for (int r = 0; r < 4; ++r) {
                    const f4 ek = *(const f4*)(ekb + r * H_ + (h4 << 2));
                    acc[r][0] = fmaf(w4[0], rcp_fast(fmaf(ek[0], e[0], 1.f)), acc[r][0]);
                    acc[r][1] = fmaf(w4[1], rcp_fast(fmaf(ek[1], e[1], 1.f)), acc[r][1]);
                    acc[r][0] = fmaf(w4[2], rcp_fast(fmaf(ek[2], e[2], 1.f)), acc[r][0]);
                    acc[r][1] = fmaf(w4[3], rcp_fast(fmaf(ek[3], e[3], 1.f)), acc[r][1]);
                }
            }
            const int q = (c << 6) + lane;
#pragma unroll
            for (int r = 0; r < 4; ++r)
                sc_s[(rh * 4 + r) * 260 + q] = sumwv - 2.f * (acc[r][0] + acc[r][1]);
        }
    }
    __syncthreads();

    // Phase 2
    {
        const float* row = sc_s + wu * 260;
        float s[4];
        float m = MASKV;
#pragma unroll
        for (int j = 0; j < 4; ++j) {
            const int q = (j << 6) + lane;
            s[j] = (q < valid) ? row[q] : MASKV;
            m = fmaxf(m, s[j]);
        }
#pragma unroll
        for (int off = 32; off >= 1; off >>= 1)
            m = fmaxf(m, __shfl_xor(m, off, 64));
        float ssum = 0.f;
#pragma unroll
        for (int j = 0; j < 4; ++j) {
            s[j] = exp2_fast(L2E * (s[j] - m));
            ssum += s[j];
        }
#pragma unroll
        for (int off = 32; off >= 1; off >>= 1)
            ssum += __shfl_xor(ssum, off, 64);
        const float inv = rcp_fast(ssum);
#pragma unroll
        for (int j = 0; j < 4; ++j)
            at_s[(((j << 6) + lane) << 3) + wu] = s[j] * inv;
    }
    __syncthreads();

    // Phase 3 (single scope: o[] live across both reduce steps)
    float* red = scratch;
    {
        const int d4 = lane << 2;
        const float* vb = value + (size_t)b * (NQ_ * DV_) + d4;
        f4 o[8];
#pragma unroll
        for (int k = 0; k < 8; ++k) o[k] = (f4){0.f, 0.f, 0.f, 0.f};
#pragma unroll 4
        for (int q = wu; q < valid; q += 8) {
            const f4 v   = *(const f4*)(vb + (size_t)q * DV_);
            const f4 alo = *(const f4*)(at_s + (q << 3));
            const f4 ahi = *(const f4*)(at_s + (q << 3) + 4);
            o[0] += alo[0] * v; o[1] += alo[1] * v;
            o[2] += alo[2] * v; o[3] += alo[3] * v;
            o[4] += ahi[0] * v; o[5] += ahi[1] * v;
            o[6] += ahi[2] * v; o[7] += ahi[3] * v;
        }
        if (wu < 4) {
            float* rp = red + (wu << 11) + d4;
#pragma unroll
            for (int k = 0; k < 8; ++k) *(f4*)(rp + (k << 8)) = o[k];
        }
        __syncthreads();
        if (wu >= 4) {
            float* rp = red + ((wu - 4) << 11) + d4;
#pragma unroll
            for (int k = 0; k < 8; ++k) {
                f4* p = (f4*)(rp + (k << 8));
                *p += o[k];
            }
        }
        __syncthreads();
        const float* rp = red + (wu << 8) + d4;
        f4 oo = *(const f4*)(rp)        + *(const f4*)(rp + 2048)
              + *(const f4*)(rp + 4096) + *(const f4*)(rp + 6144);
        *(f4*)(out + ((size_t)(b * NK_ + k0 + wu)) * DV_ + d4) = oo;
    }
}

// ---------------------------------------------------------------------------
extern "C" void kernel_launch(void* const* d_in, const int* in_sizes, int n_in,
                              void* d_out, int out_size, void* d_ws, size_t ws_size,
                              hipStream_t stream)
{
    const float* key   = (const float*)d_in[0];
    const float* query = (const float*)d_in[1];
    const float* value = (const float*)d_in[2];
    const int*   vlens = (const int*)  d_in[3];
    const float* Wk    = (const float*)d_in[4];
    const float* Wq    = (const float*)d_in[5];
    const float* wv    = (const float*)d_in[6];
    float* outp = (float*)d_out;

    float* kfE = (float*)d_ws;                        // [B][NK][H]      2 MB
    float* qE4 = kfE + (size_t)B_ * NK_ * H_;         // [B][H/4][NQ][4] 2 MB

    hipLaunchKernelGGL(proj_kernel, dim3(512), dim3(256), 0, stream,
                       key, query, Wk, Wq, kfE, qE4);
    hipLaunchKernelGGL(attn_kernel2, dim3(512), dim3(512), 0, stream,
                       kfE, qE4, value, vlens, wv, outp);
}

// Round 2
// 101.031 us; speedup vs baseline: 1.0198x; 1.0198x over previous
//
#include <hip/hip_runtime.h>

#define B_   16
#define NK_  256
#define NQ_  256
#define DK_  256
#define H_   128
#define DV_  256

// 2*log2(e): features prescaled so exp2(C2X*x) = e^{2x}
#define C2X 2.8853900817779268f
// log2(e) for softmax exp
#define L2E 1.4426950408889634f
#define MASKV -1.0e5f

typedef float f4 __attribute__((ext_vector_type(4)));
typedef short s4v    __attribute__((ext_vector_type(4)));
typedef short bf16x8 __attribute__((ext_vector_type(8)));

__device__ __forceinline__ float exp2_fast(float x) { return __builtin_amdgcn_exp2f(x); }
__device__ __forceinline__ float rcp_fast(float x)  { return __builtin_amdgcn_rcpf(x); }

// RNE float -> bf16 (upper 16 bits), returned as 16-bit pattern
__device__ __forceinline__ unsigned bf16_rne(float x) {
    unsigned u = __builtin_bit_cast(unsigned, x);
    return (u + 0x7FFFu + ((u >> 16) & 1u)) >> 16;
}
__device__ __forceinline__ float bf16_to_f(unsigned h) {
    return __builtin_bit_cast(float, h << 16);
}

// ---------------------------------------------------------------------------
// Kernel A (R9): projections via split-bf16 MFMA (3-pass: hh + lh + hl),
// rel err ~2^-17 — far below the exp2/rcp fast-math error already accepted.
// CDNA4 has no fp32 MFMA; R8's fp32 vector-FMA GEMM had a 13.6 us chip-wide
// VALU floor. MFMA path: 96 mfma_f32_16x16x32_bf16 per wave total (~0.5 us).
//   blocks 0..127   : kfE[b][k][h]      = exp2(C2X * (key  @ Wk))
//   blocks 128..255 : qE4[b][h/4][q][4] = exp2(C2X * (query @ Wq))
// Block: 256 thr (4 waves), M-tile 32 rows, N = 128 (wave w -> n-strip 32).
// A (32x256 fp32) staged+split hi/lo in LDS, rows padded to 264 shorts so
// fragment b128 reads are 2-way (free). B fragments read per-lane from
// global W (128 KB, L2-hot) and split in-register.
// MFMA layouts (guide §3, m89-verified): A: row=lane&15, k=8*(lane>>4)+j;
// B: col=lane&15, same k; C/D: col=lane&15, row=4*(lane>>4)+reg.
// ---------------------------------------------------------------------------
__global__ __launch_bounds__(256) void proj_kernel(
    const float* __restrict__ key, const float* __restrict__ query,
    const float* __restrict__ Wk,  const float* __restrict__ Wq,
    float* __restrict__ kfE, float* __restrict__ qE4)
{
    __shared__ alignas(16) short Ah_s[32 * 264];   // 16.5 KB  A hi (bf16)
    __shared__ alignas(16) short Al_s[32 * 264];   // 16.5 KB  A lo (bf16)

    const int blk = blockIdx.x;
    const int tid = threadIdx.x;
    const bool isQ = blk >= 128;
    const int mbase = (blk & 127) << 5;            // 32 rows of the 4096

    const float* __restrict__ Ag = isQ ? query : key;
    const float* __restrict__ Wg = isQ ? Wq : Wk;

    // ---- stage + hi/lo split A: 32 rows x 256 k (coalesced f4 loads)
    {
        const int r  = tid >> 3;                   // 0..31
        const int kc = (tid & 7) << 5;             // 0..224
        const f4* src = (const f4*)(Ag + (size_t)(mbase + r) * DK_ + kc);
        s4v* dh = (s4v*)(Ah_s + r * 264 + kc);
        s4v* dl = (s4v*)(Al_s + r * 264 + kc);
#pragma unroll
        for (int i = 0; i < 8; ++i) {
            f4 v = src[i];
            s4v h, l;
#pragma unroll
            for (int c = 0; c < 4; ++c) {
                unsigned hb = bf16_rne(v[c]);
                h[c] = (short)hb;
                l[c] = (short)bf16_rne(v[c] - bf16_to_f(hb));
            }
            dh[i] = h;
            dl[i] = l;
        }
    }
    __syncthreads();

    const int w  = tid >> 6;                       // wave 0..3 -> n-strip
    const int l  = tid & 63;
    const int lg = l >> 4;                         // k-group 0..3
    const int ln = l & 15;

    f4 acc[2][2] = {};                             // [m-tile][n-tile], f32x4

#pragma unroll
    for (int ks = 0; ks < 8; ++ks) {               // K = 256 in steps of 32
        const int k0 = ks << 5;

        // B fragments from global W (L2-hot), split in-register
        bf16x8 bh[2], bl[2];
#pragma unroll
        for (int nt = 0; nt < 2; ++nt) {
            const float* bp = Wg + (size_t)(k0 + (lg << 3)) * H_
                              + (w << 5) + (nt << 4) + ln;
            float bv[8];
#pragma unroll
            for (int j = 0; j < 8; ++j) bv[j] = bp[(size_t)j * H_];
#pragma unroll
            for (int j = 0; j < 8; ++j) {
                unsigned hb = bf16_rne(bv[j]);
                bh[nt][j] = (short)hb;
                bl[nt][j] = (short)bf16_rne(bv[j] - bf16_to_f(hb));
            }
        }

        // A fragments from LDS (b128, 2-way-free via 264-short row pad)
        bf16x8 ah[2], al[2];
#pragma unroll
        for (int mt = 0; mt < 2; ++mt) {
            const int m = (mt << 4) + ln;
            ah[mt] = *(const bf16x8*)(Ah_s + m * 264 + k0 + (lg << 3));
            al[mt] = *(const bf16x8*)(Al_s + m * 264 + k0 + (lg << 3));
        }

        // 12 MFMAs: hh + lh + hl (lo*lo dropped, ~2^-18)
#pragma unroll
        for (int mt = 0; mt < 2; ++mt)
#pragma unroll
            for (int nt = 0; nt < 2; ++nt) {
                acc[mt][nt] = __builtin_amdgcn_mfma_f32_16x16x32_bf16(
                    ah[mt], bh[nt], acc[mt][nt], 0, 0, 0);
                acc[mt][nt] = __builtin_amdgcn_mfma_f32_16x16x32_bf16(
                    al[mt], bh[nt], acc[mt][nt], 0, 0, 0);
                acc[mt][nt] = __builtin_amdgcn_mfma_f32_16x16x32_bf16(
                    ah[mt], bl[nt], acc[mt][nt], 0, 0, 0);
            }
    }

    // ---- epilogue: exp2(C2X * acc) -> kfE / qE4 layouts
#pragma unroll
    for (int mt = 0; mt < 2; ++mt)
#pragma unroll
        for (int nt = 0; nt < 2; ++nt)
#pragma unroll
            for (int r = 0; r < 4; ++r) {
                const float e = exp2_fast(C2X * acc[mt][nt][r]);
                const int R = mbase + (mt << 4) + (lg << 2) + r;   // global row
                const int h = (w << 5) + (nt << 4) + ln;           // 0..127
                if (!isQ) {
                    kfE[(size_t)R * H_ + h] = e;
                } else {
                    const int b = R >> 8, q = R & 255;
                    qE4[(((size_t)(b * 32 + (h >> 2))) * NQ_ + q) * 4 + (h & 3)] = e;
                }
            }
}

// ---------------------------------------------------------------------------
// Kernel B (unchanged from R8's attn_kernel2; dead duplicate removed).
// 8 k-rows/block, 512 blocks x 512 threads, 40 KB LDS, 2 blocks/CU.
// Phase 1: wave (chunk c=wu>>1, row-half rh=wu&1) -> 4 k-rows x 64 q.
// Phase 2: wave wu -> k-row wu masked softmax.
// Phase 3: 8 q-streams, value read once/block, two-step LDS reduce.
// ---------------------------------------------------------------------------
__global__ __launch_bounds__(512, 4) void attn_kernel(
    const float* __restrict__ kfE, const float* __restrict__ qE4,
    const float* __restrict__ value, const int* __restrict__ vlens,
    const float* __restrict__ wv, float* __restrict__ out)
{
    __shared__ alignas(16) float at_s[256 * 8];
    __shared__ alignas(16) float scratch[8192];

    const int x    = blockIdx.x;
    const int g    = x >> 4;
    const int b    = ((x & 15) + ((x >> 8) << 3)) & 15;
    const int k0   = g << 3;
    const int tid  = threadIdx.x;
    const int lane = tid & 63;
    const int wu   = __builtin_amdgcn_readfirstlane(tid >> 6);
    const int valid  = vlens[b];
    const int nchunk = (valid + 63) >> 6;

    float sumwv;
    {
        f4 sw = {0.f, 0.f, 0.f, 0.f};
#pragma unroll
        for (int i = 0; i < 32; ++i) sw += ((const f4*)wv)[i];
        sumwv = (sw[0] + sw[1]) + (sw[2] + sw[3]);
    }

    float* sc_s = scratch;

    // Phase 1
    {
        const int c  = wu >> 1;
        const int rh = wu & 1;
        if (c < nchunk) {
            const float* ekb = kfE + ((size_t)(b * NK_ + k0 + rh * 4)) * H_;
            const f4*    eqp = (const f4*)qE4 + ((size_t)b << 13) + (c << 6) + lane;
            const f4*    wvf = (const f4*)wv;
            float acc[4][2];
#pragma unroll
            for (int r = 0; r < 4; ++r) { acc[r][0] = 0.f; acc[r][1] = 0.f; }
#pragma unroll 4
            for (int h4 = 0; h4 < 32; ++h4) {
                const f4 e  = eqp[h4 << 8];
                const f4 w4 = wvf[h4];
#pragma unroll
                for (int r = 0; r < 4; ++r) {
                    const f4 ek = *(const f4*)(ekb + r * H_ + (h4 << 2));
                    acc[r][0] = fmaf(w4[0], rcp_fast(fmaf(ek[0], e[0], 1.f)), acc[r][0]);
                    acc[r][1] = fmaf(w4[1], rcp_fast(fmaf(ek[1], e[1], 1.f)), acc[r][1]);
                    acc[r][0] = fmaf(w4[2], rcp_fast(fmaf(ek[2], e[2], 1.f)), acc[r][0]);
                    acc[r][1] = fmaf(w4[3], rcp_fast(fmaf(ek[3], e[3], 1.f)), acc[r][1]);
                }
            }
            const int q = (c << 6) + lane;
#pragma unroll
            for (int r = 0; r < 4; ++r)
                sc_s[(rh * 4 + r) * 260 + q] = sumwv - 2.f * (acc[r][0] + acc[r][1]);
        }
    }
    __syncthreads();

    // Phase 2
    {
        const float* row = sc_s + wu * 260;
        float s[4];
        float m = MASKV;
#pragma unroll
        for (int j = 0; j < 4; ++j) {
            const int q = (j << 6) + lane;
            s[j] = (q < valid) ? row[q] : MASKV;
            m = fmaxf(m, s[j]);
        }
#pragma unroll
        for (int off = 32; off >= 1; off >>= 1)
            m = fmaxf(m, __shfl_xor(m, off, 64));
        float ssum = 0.f;
#pragma unroll
        for (int j = 0; j < 4; ++j) {
            s[j] = exp2_fast(L2E * (s[j] - m));
            ssum += s[j];
        }
#pragma unroll
        for (int off = 32; off >= 1; off >>= 1)
            ssum += __shfl_xor(ssum, off, 64);
        const float inv = rcp_fast(ssum);
#pragma unroll
        for (int j = 0; j < 4; ++j)
            at_s[(((j << 6) + lane) << 3) + wu] = s[j] * inv;
    }
    __syncthreads();

    // Phase 3
    float* red = scratch;
    {
        const int d4 = lane << 2;
        const float* vb = value + (size_t)b * (NQ_ * DV_) + d4;
        f4 o[8];
#pragma unroll
        for (int k = 0; k < 8; ++k) o[k] = (f4){0.f, 0.f, 0.f, 0.f};
#pragma unroll 4
        for (int q = wu; q < valid; q += 8) {
            const f4 v   = *(const f4*)(vb + (size_t)q * DV_);
            const f4 alo = *(const f4*)(at_s + (q << 3));
            const f4 ahi = *(const f4*)(at_s + (q << 3) + 4);
            o[0] += alo[0] * v; o[1] += alo[1] * v;
            o[2] += alo[2] * v; o[3] += alo[3] * v;
            o[4] += ahi[0] * v; o[5] += ahi[1] * v;
            o[6] += ahi[2] * v; o[7] += ahi[3] * v;
        }
        if (wu < 4) {
            float* rp = red + (wu << 11) + d4;
#pragma unroll
            for (int k = 0; k < 8; ++k) *(f4*)(rp + (k << 8)) = o[k];
        }
        __syncthreads();
        if (wu >= 4) {
            float* rp = red + ((wu - 4) << 11) + d4;
#pragma unroll
            for (int k = 0; k < 8; ++k) {
                f4* p = (f4*)(rp + (k << 8));
                *p += o[k];
            }
        }
        __syncthreads();
        const float* rp = red + (wu << 8) + d4;
        f4 oo = *(const f4*)(rp)        + *(const f4*)(rp + 2048)
              + *(const f4*)(rp + 4096) + *(const f4*)(rp + 6144);
        *(f4*)(out + ((size_t)(b * NK_ + k0 + wu)) * DV_ + d4) = oo;
    }
}

// ---------------------------------------------------------------------------
extern "C" void kernel_launch(void* const* d_in, const int* in_sizes, int n_in,
                              void* d_out, int out_size, void* d_ws, size_t ws_size,
                              hipStream_t stream)
{
    const float* key   = (const float*)d_in[0];
    const float* query = (const float*)d_in[1];
    const float* value = (const float*)d_in[2];
    const int*   vlens = (const int*)  d_in[3];
    const float* Wk    = (const float*)d_in[4];
    const float* Wq    = (const float*)d_in[5];
    const float* wv    = (const float*)d_in[6];
    float* outp = (float*)d_out;

    float* kfE = (float*)d_ws;                        // [B][NK][H]      2 MB
    float* qE4 = kfE + (size_t)B_ * NK_ * H_;         // [B][H/4][NQ][4] 2 MB

    hipLaunchKernelGGL(proj_kernel, dim3(256), dim3(256), 0, stream,
                       key, query, Wk, Wq, kfE, qE4);
    hipLaunchKernelGGL(attn_kernel, dim3(512), dim3(512), 0, stream,
                       kfE, qE4, value, vlens, wv, outp);
}

// Round 4
// 100.668 us; speedup vs baseline: 1.0235x; 1.0036x over previous
//
#include <hip/hip_runtime.h>

#define B_   16
#define NK_  256
#define NQ_  256
#define DK_  256
#define H_   128
#define DV_  256

// 2*log2(e): features prescaled so exp2(C2X*x) = e^{2x}
#define C2X 2.8853900817779268f
// log2(e) for softmax exp
#define L2E 1.4426950408889634f
#define MASKV -1.0e5f

typedef float f4 __attribute__((ext_vector_type(4)));
typedef short s4v    __attribute__((ext_vector_type(4)));
typedef short bf16x8 __attribute__((ext_vector_type(8)));

__device__ __forceinline__ float exp2_fast(float x) { return __builtin_amdgcn_exp2f(x); }
__device__ __forceinline__ float rcp_fast(float x)  { return __builtin_amdgcn_rcpf(x); }

// RNE float -> bf16 (upper 16 bits), returned as 16-bit pattern
__device__ __forceinline__ unsigned bf16_rne(float x) {
    unsigned u = __builtin_bit_cast(unsigned, x);
    return (u + 0x7FFFu + ((u >> 16) & 1u)) >> 16;
}
__device__ __forceinline__ float bf16_to_f(unsigned h) {
    return __builtin_bit_cast(float, h << 16);
}

// ---------------------------------------------------------------------------
// Kernel A (R10, resubmitted after R3 infra failure): split-bf16 MFMA
// projections, latency/coalescing fixed.
// R9 post-mortem: 1 block/CU (zero latency hiding for the 128 stride-512B
// scalar B-loads), pointless A LDS staging, 16 scattered dword stores/thread.
// R10: M-tile 16 rows, 512 blocks (2 blocks/CU, 2 waves/SIMD); A-fragments
// direct from global (block's A = 16 KB, L1-resident); epilogue through an
// 8.25 KB padded LDS tile -> fully coalesced f4 stores for both layouts.
// Fragment mapping + 3-pass (hh+lh+hl) math identical to R9 (verified).
//   blocks 0..255   : kfE[b][k][h]      = exp2(C2X * (key  @ Wk))
//   blocks 256..511 : qE4[b][h/4][q][4] = exp2(C2X * (query @ Wq))
// ---------------------------------------------------------------------------
__global__ __launch_bounds__(256) void proj_kernel(
    const float* __restrict__ key, const float* __restrict__ query,
    const float* __restrict__ Wk,  const float* __restrict__ Wq,
    float* __restrict__ kfE, float* __restrict__ qE4)
{
    __shared__ alignas(16) float E_s[16 * 132];    // epilogue tile, 8.25 KB

    const int blk = blockIdx.x;                    // 512
    const int tid = threadIdx.x;
    const bool isQ = blk >= 256;
    const int mbase = (blk & 255) << 4;            // 16 rows of the 4096

    const float* __restrict__ Ag = isQ ? query : key;
    const float* __restrict__ Wg = isQ ? Wq : Wk;

    const int w  = tid >> 6;                       // wave 0..3 -> n-strip 32
    const int l  = tid & 63;
    const int lg = l >> 4;                         // k-group 0..3
    const int ln = l & 15;

    f4 acc[2] = {};                                // [n-tile], f32x4

    const float* arow = Ag + (size_t)(mbase + ln) * DK_ + (lg << 3);

#pragma unroll
    for (int ks = 0; ks < 8; ++ks) {               // K = 256 in steps of 32
        const int k0 = ks << 5;

        // A fragment: 8 consecutive fp32 (row ln, cols k0+8*lg ..+8), L1-hot
        bf16x8 ah, al;
        {
            const f4 a0 = *(const f4*)(arow + k0);
            const f4 a1 = *(const f4*)(arow + k0 + 4);
            float av[8] = {a0[0], a0[1], a0[2], a0[3], a1[0], a1[1], a1[2], a1[3]};
#pragma unroll
            for (int j = 0; j < 8; ++j) {
                unsigned hb = bf16_rne(av[j]);
                ah[j] = (short)hb;
                al[j] = (short)bf16_rne(av[j] - bf16_to_f(hb));
            }
        }

        // B fragments from global W (128 KB, L2-hot), split in-register
        bf16x8 bh[2], bl[2];
#pragma unroll
        for (int nt = 0; nt < 2; ++nt) {
            const float* bp = Wg + (size_t)(k0 + (lg << 3)) * H_
                              + (w << 5) + (nt << 4) + ln;
            float bv[8];
#pragma unroll
            for (int j = 0; j < 8; ++j) bv[j] = bp[(size_t)j * H_];
#pragma unroll
            for (int j = 0; j < 8; ++j) {
                unsigned hb = bf16_rne(bv[j]);
                bh[nt][j] = (short)hb;
                bl[nt][j] = (short)bf16_rne(bv[j] - bf16_to_f(hb));
            }
        }

        // 6 MFMAs: hh + lh + hl (lo*lo dropped, ~2^-18)
#pragma unroll
        for (int nt = 0; nt < 2; ++nt) {
            acc[nt] = __builtin_amdgcn_mfma_f32_16x16x32_bf16(ah, bh[nt], acc[nt], 0, 0, 0);
            acc[nt] = __builtin_amdgcn_mfma_f32_16x16x32_bf16(al, bh[nt], acc[nt], 0, 0, 0);
            acc[nt] = __builtin_amdgcn_mfma_f32_16x16x32_bf16(ah, bl[nt], acc[nt], 0, 0, 0);
        }
    }

    // ---- epilogue: exp2(C2X*acc) -> LDS tile (writes 2-way-free via pad 132)
    // C/D layout: col = w*32 + nt*16 + ln, row = 4*lg + r
#pragma unroll
    for (int nt = 0; nt < 2; ++nt)
#pragma unroll
        for (int r = 0; r < 4; ++r)
            E_s[((lg << 2) + r) * 132 + (w << 5) + (nt << 4) + ln] =
                exp2_fast(C2X * acc[nt][r]);
    __syncthreads();

    // ---- coalesced stores from the tile
    if (!isQ) {
        // kfE row-major [16][128]: 512 f4, 2 per thread
#pragma unroll
        for (int i = 0; i < 2; ++i) {
            const int idx = tid + (i << 8);        // f4 index
            const int r   = idx >> 5;
            const int c4  = (idx & 31) << 2;
            *(f4*)(kfE + (size_t)(mbase + r) * H_ + c4) =
                *(const f4*)(E_s + r * 132 + c4);
        }
    } else {
        // qE4[(b*32+h4)*256 + q] f4 = 4 h-values of one q
        const int b  = mbase >> 8;
        const int q0 = mbase & 255;
        f4* dstb = (f4*)qE4 + (size_t)b * (32 * NQ_) + q0;
#pragma unroll
        for (int i = 0; i < 2; ++i) {
            const int h4   = (tid >> 4) + (i << 4);  // 0..31
            const int qloc = tid & 15;               // 16 consecutive lanes = 16 q
            dstb[(size_t)h4 * NQ_ + qloc] =
                *(const f4*)(E_s + qloc * 132 + (h4 << 2));
        }
    }
}

// ---------------------------------------------------------------------------
// Kernel B (byte-identical to R9).
// 8 k-rows/block, 512 blocks x 512 threads, 40 KB LDS, 2 blocks/CU.
// ---------------------------------------------------------------------------
__global__ __launch_bounds__(512, 4) void attn_kernel(
    const float* __restrict__ kfE, const float* __restrict__ qE4,
    const float* __restrict__ value, const int* __restrict__ vlens,
    const float* __restrict__ wv, float* __restrict__ out)
{
    __shared__ alignas(16) float at_s[256 * 8];
    __shared__ alignas(16) float scratch[8192];

    const int x    = blockIdx.x;
    const int g    = x >> 4;
    const int b    = ((x & 15) + ((x >> 8) << 3)) & 15;
    const int k0   = g << 3;
    const int tid  = threadIdx.x;
    const int lane = tid & 63;
    const int wu   = __builtin_amdgcn_readfirstlane(tid >> 6);
    const int valid  = vlens[b];
    const int nchunk = (valid + 63) >> 6;

    float sumwv;
    {
        f4 sw = {0.f, 0.f, 0.f, 0.f};
#pragma unroll
        for (int i = 0; i < 32; ++i) sw += ((const f4*)wv)[i];
        sumwv = (sw[0] + sw[1]) + (sw[2] + sw[3]);
    }

    float* sc_s = scratch;

    // Phase 1
    {
        const int c  = wu >> 1;
        const int rh = wu & 1;
        if (c < nchunk) {
            const float* ekb = kfE + ((size_t)(b * NK_ + k0 + rh * 4)) * H_;
            const f4*    eqp = (const f4*)qE4 + ((size_t)b << 13) + (c << 6) + lane;
            const f4*    wvf = (const f4*)wv;
            float acc[4][2];
#pragma unroll
            for (int r = 0; r < 4; ++r) { acc[r][0] = 0.f; acc[r][1] = 0.f; }
#pragma unroll 4
            for (int h4 = 0; h4 < 32; ++h4) {
                const f4 e  = eqp[h4 << 8];
                const f4 w4 = wvf[h4];
#pragma unroll
                for (int r = 0; r < 4; ++r) {
                    const f4 ek = *(const f4*)(ekb + r * H_ + (h4 << 2));
                    acc[r][0] = fmaf(w4[0], rcp_fast(fmaf(ek[0], e[0], 1.f)), acc[r][0]);
                    acc[r][1] = fmaf(w4[1], rcp_fast(fmaf(ek[1], e[1], 1.f)), acc[r][1]);
                    acc[r][0] = fmaf(w4[2], rcp_fast(fmaf(ek[2], e[2], 1.f)), acc[r][0]);
                    acc[r][1] = fmaf(w4[3], rcp_fast(fmaf(ek[3], e[3], 1.f)), acc[r][1]);
                }
            }
            const int q = (c << 6) + lane;
#pragma unroll
            for (int r = 0; r < 4; ++r)
                sc_s[(rh * 4 + r) * 260 + q] = sumwv - 2.f * (acc[r][0] + acc[r][1]);
        }
    }
    __syncthreads();

    // Phase 2
    {
        const float* row = sc_s + wu * 260;
        float s[4];
        float m = MASKV;
#pragma unroll
        for (int j = 0; j < 4; ++j) {
            const int q = (j << 6) + lane;
            s[j] = (q < valid) ? row[q] : MASKV;
            m = fmaxf(m, s[j]);
        }
#pragma unroll
        for (int off = 32; off >= 1; off >>= 1)
            m = fmaxf(m, __shfl_xor(m, off, 64));
        float ssum = 0.f;
#pragma unroll
        for (int j = 0; j < 4; ++j) {
            s[j] = exp2_fast(L2E * (s[j] - m));
            ssum += s[j];
        }
#pragma unroll
        for (int off = 32; off >= 1; off >>= 1)
            ssum += __shfl_xor(ssum, off, 64);
        const float inv = rcp_fast(ssum);
#pragma unroll
        for (int j = 0; j < 4; ++j)
            at_s[(((j << 6) + lane) << 3) + wu] = s[j] * inv;
    }
    __syncthreads();

    // Phase 3
    float* red = scratch;
    {
        const int d4 = lane << 2;
        const float* vb = value + (size_t)b * (NQ_ * DV_) + d4;
        f4 o[8];
#pragma unroll
        for (int k = 0; k < 8; ++k) o[k] = (f4){0.f, 0.f, 0.f, 0.f};
#pragma unroll 4
        for (int q = wu; q < valid; q += 8) {
            const f4 v   = *(const f4*)(vb + (size_t)q * DV_);
            const f4 alo = *(const f4*)(at_s + (q << 3));
            const f4 ahi = *(const f4*)(at_s + (q << 3) + 4);
            o[0] += alo[0] * v; o[1] += alo[1] * v;
            o[2] += alo[2] * v; o[3] += alo[3] * v;
            o[4] += ahi[0] * v; o[5] += ahi[1] * v;
            o[6] += ahi[2] * v; o[7] += ahi[3] * v;
        }
        if (wu < 4) {
            float* rp = red + (wu << 11) + d4;
#pragma unroll
            for (int k = 0; k < 8; ++k) *(f4*)(rp + (k << 8)) = o[k];
        }
        __syncthreads();
        if (wu >= 4) {
            float* rp = red + ((wu - 4) << 11) + d4;
#pragma unroll
            for (int k = 0; k < 8; ++k) {
                f4* p = (f4*)(rp + (k << 8));
                *p += o[k];
            }
        }
        __syncthreads();
        const float* rp = red + (wu << 8) + d4;
        f4 oo = *(const f4*)(rp)        + *(const f4*)(rp + 2048)
              + *(const f4*)(rp + 4096) + *(const f4*)(rp + 6144);
        *(f4*)(out + ((size_t)(b * NK_ + k0 + wu)) * DV_ + d4) = oo;
    }
}

// ---------------------------------------------------------------------------
extern "C" void kernel_launch(void* const* d_in, const int* in_sizes, int n_in,
                              void* d_out, int out_size, void* d_ws, size_t ws_size,
                              hipStream_t stream)
{
    const float* key   = (const float*)d_in[0];
    const float* query = (const float*)d_in[1];
    const float* value = (const float*)d_in[2];
    const int*   vlens = (const int*)  d_in[3];
    const float* Wk    = (const float*)d_in[4];
    const float* Wq    = (const float*)d_in[5];
    const float* wv    = (const float*)d_in[6];
    float* outp = (float*)d_out;

    float* kfE = (float*)d_ws;                        // [B][NK][H]      2 MB
    float* qE4 = kfE + (size_t)B_ * NK_ * H_;         // [B][H/4][NQ][4] 2 MB

    hipLaunchKernelGGL(proj_kernel, dim3(512), dim3(256), 0, stream,
                       key, query, Wk, Wq, kfE, qE4);
    hipLaunchKernelGGL(attn_kernel, dim3(512), dim3(512), 0, stream,
                       kfE, qE4, value, vlens, wv, outp);
}